// Round 3
// baseline (404.052 us; speedup 1.0000x reference)
//
#include <hip/hip_runtime.h>

#define TPB   256
#define LSTEP 16      // steps per chunk; 64 lanes * 16 = 1024 steps

// Frame matrix stored as three COLUMN vectors in chunk-local coords
// (col j = image of chunk-start basis vector j).
// Compose (O, od) ∘ (A, d) = (O·A, od + O·d) with the convention
// (O·v).x = v.x*o0x + v.y*o1x + v.z*o2x  etc.

__global__ __launch_bounds__(TPB) void particle_scan_kernel(
    const float* __restrict__ x0p,
    const float* __restrict__ e0p,
    const float* __restrict__ e1p,
    const float* __restrict__ e2p,
    const float* __restrict__ sp,
    const float* __restrict__ pa,
    const float* __restrict__ na,
    const int*   __restrict__ dtp,
    float* __restrict__ out,
    int B, int N)
{
    const int tid  = threadIdx.x;
    const int lane = tid & 63;
    const int b    = (int)blockIdx.x * (TPB / 64) + (tid >> 6);   // particle
    const long long BN = (long long)B * N;
    const long long off_X      = N;
    const long long off_states = off_X + BN * 3;
    const long long off_speeds = off_states + BN;
    const long long off_pa     = off_speeds + BN;
    const long long off_na     = off_pa + BN;

    // ---- ts = arange(N) * dt ----
    {
        int flat = (int)blockIdx.x * TPB + tid;
        if (flat < N) out[flat] = (float)flat * (float)dtp[0];
    }

    const long long base = (long long)b * N + (long long)lane * LSTEP;

    // ---- pass 1 fused with input load + passthrough/zero writes ----
    // Track frame matrix A (cols a0,a1,a2) and per-step cumulative local
    // displacement dl[t], all in chunk-start coordinates.
    float a0x = 1.f, a0y = 0.f, a0z = 0.f;
    float a1x = 0.f, a1y = 1.f, a1z = 0.f;
    float a2x = 0.f, a2y = 0.f, a2z = 1.f;
    float dx = 0.f, dy = 0.f, dz = 0.f;
    float dlx[LSTEP], dly[LSTEP], dlz[LSTEP];

    {
        const float4* s4 = reinterpret_cast<const float4*>(sp + base);
        const float4* p4 = reinterpret_cast<const float4*>(pa + base);
        const float4* q4 = reinterpret_cast<const float4*>(na + base);
        float4* os = reinterpret_cast<float4*>(out + off_speeds + base);
        float4* op = reinterpret_cast<float4*>(out + off_pa     + base);
        float4* oq = reinterpret_cast<float4*>(out + off_na     + base);
        float4* oz = reinterpret_cast<float4*>(out + off_states + base);
        const float4 z4 = make_float4(0.f, 0.f, 0.f, 0.f);

        #pragma unroll
        for (int g = 0; g < LSTEP / 4; ++g) {
            float4 sv = s4[g], pv = p4[g], qv = q4[g];
            os[g] = sv; op[g] = pv; oq[g] = qv; oz[g] = z4;
            float ss[4] = { sv.x, sv.y, sv.z, sv.w };
            float pp[4] = { pv.x, pv.y, pv.z, pv.w };
            float qq[4] = { qv.x, qv.y, qv.z, qv.w };
            #pragma unroll
            for (int j = 0; j < 4; ++j) {
                const int t = 4 * g + j;
                float s1, c1, s2, c2;
                __sincosf(pp[j], &s1, &c1);
                __sincosf(qq[j], &s2, &c2);
                // planar rotation about col2
                float t0x = c1*a0x + s1*a1x, t0y = c1*a0y + s1*a1y, t0z = c1*a0z + s1*a1z;
                float t1x = c1*a1x - s1*a0x, t1y = c1*a1y - s1*a0y, t1z = c1*a1z - s1*a0z;
                // nonplanar rotation about (new) col1
                float u0x = c2*t0x - s2*a2x, u0y = c2*t0y - s2*a2y, u0z = c2*t0z - s2*a2z;
                float u2x = c2*a2x + s2*t0x, u2y = c2*a2y + s2*t0y, u2z = c2*a2z + s2*t0z;
                a0x = u0x; a0y = u0y; a0z = u0z;
                a1x = t1x; a1y = t1y; a1z = t1z;
                a2x = u2x; a2y = u2y; a2z = u2z;
                dx = fmaf(ss[j], a0x, dx);
                dy = fmaf(ss[j], a0y, dy);
                dz = fmaf(ss[j], a0z, dz);
                dlx[t] = dx; dly[t] = dy; dlz[t] = dz;
            }
        }
    }

    // ---- wave-level inclusive scan (Hillis-Steele), non-commutative compose ----
    #define SCAN_STEP(K)                                                          \
    {                                                                             \
        float o0x=__shfl_up(a0x,K), o0y=__shfl_up(a0y,K), o0z=__shfl_up(a0z,K);   \
        float o1x=__shfl_up(a1x,K), o1y=__shfl_up(a1y,K), o1z=__shfl_up(a1z,K);   \
        float o2x=__shfl_up(a2x,K), o2y=__shfl_up(a2y,K), o2z=__shfl_up(a2z,K);   \
        float odx=__shfl_up(dx,K),  ody=__shfl_up(dy,K),  odz=__shfl_up(dz,K);    \
        if (lane >= K) {                                                          \
            float n0x = a0x*o0x + a0y*o1x + a0z*o2x;                              \
            float n0y = a0x*o0y + a0y*o1y + a0z*o2y;                              \
            float n0z = a0x*o0z + a0y*o1z + a0z*o2z;                              \
            float n1x = a1x*o0x + a1y*o1x + a1z*o2x;                              \
            float n1y = a1x*o0y + a1y*o1y + a1z*o2y;                              \
            float n1z = a1x*o0z + a1y*o1z + a1z*o2z;                              \
            float n2x = a2x*o0x + a2y*o1x + a2z*o2x;                              \
            float n2y = a2x*o0y + a2y*o1y + a2z*o2y;                              \
            float n2z = a2x*o0z + a2y*o1z + a2z*o2z;                              \
            float ndx = odx + dx*o0x + dy*o1x + dz*o2x;                           \
            float ndy = ody + dx*o0y + dy*o1y + dz*o2y;                           \
            float ndz = odz + dx*o0z + dy*o1z + dz*o2z;                           \
            a0x=n0x; a0y=n0y; a0z=n0z;                                            \
            a1x=n1x; a1y=n1y; a1z=n1z;                                            \
            a2x=n2x; a2y=n2y; a2z=n2z;                                            \
            dx=ndx; dy=ndy; dz=ndz;                                               \
        }                                                                         \
    }
    SCAN_STEP(1) SCAN_STEP(2) SCAN_STEP(4) SCAN_STEP(8) SCAN_STEP(16) SCAN_STEP(32)
    #undef SCAN_STEP

    // ---- shift to exclusive (lane 0 = identity) ----
    {
        float e0x=__shfl_up(a0x,1), e0y=__shfl_up(a0y,1), e0z=__shfl_up(a0z,1);
        float e1x=__shfl_up(a1x,1), e1y=__shfl_up(a1y,1), e1z=__shfl_up(a1z,1);
        float e2x=__shfl_up(a2x,1), e2y=__shfl_up(a2y,1), e2z=__shfl_up(a2z,1);
        float edx=__shfl_up(dx,1),  edy=__shfl_up(dy,1),  edz=__shfl_up(dz,1);
        if (lane == 0) {
            e0x=1.f; e0y=0.f; e0z=0.f;
            e1x=0.f; e1y=1.f; e1z=0.f;
            e2x=0.f; e2y=0.f; e2z=1.f;
            edx=0.f; edy=0.f; edz=0.f;
        }
        a0x=e0x; a0y=e0y; a0z=e0z;
        a1x=e1x; a1y=e1y; a1z=e1z;
        a2x=e2x; a2y=e2y; a2z=e2z;
        dx=edx; dy=edy; dz=edz;
    }

    // ---- compose with initial world frame F0 (columns e0,e1,e2) and x0:
    //      gk = world image of chunk-start basis vector k; Xw = world position
    //      at chunk start.
    float f0x = e0p[3*b], f0y = e0p[3*b+1], f0z = e0p[3*b+2];
    float f1x = e1p[3*b], f1y = e1p[3*b+1], f1z = e1p[3*b+2];
    float f2x = e2p[3*b], f2y = e2p[3*b+1], f2z = e2p[3*b+2];
    float Xx  = x0p[3*b], Xy  = x0p[3*b+1], Xz  = x0p[3*b+2];

    float g0x = a0x*f0x + a0y*f1x + a0z*f2x;
    float g0y = a0x*f0y + a0y*f1y + a0z*f2y;
    float g0z = a0x*f0z + a0y*f1z + a0z*f2z;
    float g1x = a1x*f0x + a1y*f1x + a1z*f2x;
    float g1y = a1x*f0y + a1y*f1y + a1z*f2y;
    float g1z = a1x*f0z + a1y*f1z + a1z*f2z;
    float g2x = a2x*f0x + a2y*f1x + a2z*f2x;
    float g2y = a2x*f0y + a2y*f1y + a2z*f2y;
    float g2z = a2x*f0z + a2y*f1z + a2z*f2z;
    Xx += dx*f0x + dy*f1x + dz*f2x;
    Xy += dx*f0y + dy*f1y + dz*f2y;
    Xz += dx*f0z + dy*f1z + dz*f2z;

    // ---- pass 2: affine transform of stored local displacements, float4 stores ----
    float* Xb = out + off_X + base * 3;
    #pragma unroll
    for (int g = 0; g < LSTEP / 4; ++g) {
        float px[12];
        #pragma unroll
        for (int j = 0; j < 4; ++j) {
            const int t = 4 * g + j;
            px[3*j+0] = fmaf(dlx[t], g0x, fmaf(dly[t], g1x, fmaf(dlz[t], g2x, Xx)));
            px[3*j+1] = fmaf(dlx[t], g0y, fmaf(dly[t], g1y, fmaf(dlz[t], g2y, Xy)));
            px[3*j+2] = fmaf(dlx[t], g0z, fmaf(dly[t], g1z, fmaf(dlz[t], g2z, Xz)));
        }
        float4* o4 = reinterpret_cast<float4*>(Xb + 12 * g);
        o4[0] = make_float4(px[0], px[1],  px[2],  px[3]);
        o4[1] = make_float4(px[4], px[5],  px[6],  px[7]);
        o4[2] = make_float4(px[8], px[9],  px[10], px[11]);
    }
}

extern "C" void kernel_launch(void* const* d_in, const int* in_sizes, int n_in,
                              void* d_out, int out_size, void* d_ws, size_t ws_size,
                              hipStream_t stream)
{
    const float* x0  = (const float*)d_in[0];
    const float* e0i = (const float*)d_in[1];
    const float* e1i = (const float*)d_in[2];
    const float* e2i = (const float*)d_in[3];
    const float* sp  = (const float*)d_in[4];
    const float* pa  = (const float*)d_in[5];
    const float* na  = (const float*)d_in[6];
    const int*   dtp = (const int*)d_in[8];

    int B = in_sizes[0] / 3;        // 8192
    int N = in_sizes[4] / B;        // 1024

    int nBlocks = B / (TPB / 64);   // one wave per particle -> 2048 blocks
    particle_scan_kernel<<<dim3(nBlocks), dim3(TPB), 0, stream>>>(
        x0, e0i, e1i, e2i, sp, pa, na, dtp, (float*)d_out, B, N);
}